// Round 1
// baseline (2282.260 us; speedup 1.0000x reference)
//
#include <hip/hip_runtime.h>

#define NB 2          // batches per workgroup
#define TT 256        // timesteps
#define II 6          // input features
#define HH 64         // hidden size
#define NG 192        // 3*HH gate rows

__device__ __forceinline__ float fsigm(float v) {
    // sigmoid(v) = 1/(1+2^(-v*log2 e)).  Large |v| safe: rcp(inf)=0.
    float e = __builtin_amdgcn_exp2f(-1.44269504f * v);
    return __builtin_amdgcn_rcpf(1.0f + e);
}
__device__ __forceinline__ float ftanh(float v) {
    v = fminf(20.0f, fmaxf(-20.0f, v));                 // avoid inf*0 = NaN
    float e = __builtin_amdgcn_exp2f(-2.88539008f * v); // exp(-2v)
    return (1.0f - e) * __builtin_amdgcn_rcpf(1.0f + e);
}

__global__ __launch_bounds__(192, 2)
void gru2_fused(const float* __restrict__ x,
                const float* __restrict__ Wih0, const float* __restrict__ Whh0,
                const float* __restrict__ bih0, const float* __restrict__ bhh0,
                const float* __restrict__ Wih1, const float* __restrict__ Whh1,
                const float* __restrict__ bih1, const float* __restrict__ bhh1,
                const float* __restrict__ Wfc,  const float* __restrict__ bfc,
                float* __restrict__ out)
{
    __shared__ __align__(16) float xbuf[NB * TT * II];   // 12 KB
    __shared__ __align__(16) float h0buf[NB][HH];
    __shared__ __align__(16) float h1buf[NB][HH];
    __shared__ __align__(16) float rbuf[NB][HH];
    __shared__ __align__(16) float zbuf[NB][HH];

    const int tid  = threadIdx.x;
    const int wid  = tid >> 6;      // 0:r 1:z 2:n
    const int lane = tid & 63;
    const int row  = tid;           // gate row 0..191
    const int b0   = blockIdx.x * NB;

    // ---- preload x for NB batches (contiguous NB*1536 floats), coalesced
    {
        const float4* src = (const float4*)(x + (size_t)b0 * TT * II);
        float4* dst = (float4*)xbuf;
        #pragma unroll
        for (int k = 0; k < (NB * TT * II / 4) / 192; ++k)
            dst[tid + k * 192] = src[tid + k * 192];
    }
    if (tid < NB * HH) {
        ((float*)h0buf)[tid] = 0.0f;
        ((float*)h1buf)[tid] = 0.0f;
    }

    // ---- per-lane weight rows -> registers (constant-indexed, fully unrolled)
    float wih0[II], whh0[HH], wih1[HH], whh1[HH];
    #pragma unroll
    for (int k = 0; k < II; ++k) wih0[k] = Wih0[row * II + k];
    {
        const float4* p = (const float4*)(Whh0 + row * HH);
        #pragma unroll
        for (int k = 0; k < HH / 4; ++k) {
            float4 v = p[k];
            whh0[4*k+0] = v.x; whh0[4*k+1] = v.y; whh0[4*k+2] = v.z; whh0[4*k+3] = v.w;
        }
    }
    {
        const float4* p = (const float4*)(Wih1 + row * HH);
        #pragma unroll
        for (int k = 0; k < HH / 4; ++k) {
            float4 v = p[k];
            wih1[4*k+0] = v.x; wih1[4*k+1] = v.y; wih1[4*k+2] = v.z; wih1[4*k+3] = v.w;
        }
    }
    {
        const float4* p = (const float4*)(Whh1 + row * HH);
        #pragma unroll
        for (int k = 0; k < HH / 4; ++k) {
            float4 v = p[k];
            whh1[4*k+0] = v.x; whh1[4*k+1] = v.y; whh1[4*k+2] = v.z; whh1[4*k+3] = v.w;
        }
    }
    const float bi0 = bih0[row], bh0 = bhh0[row];
    const float bi1 = bih1[row], bh1 = bhh1[row];

    __syncthreads();

    float xnS[NB], hnS[NB];   // wave2 carries xn/hn across the barrier

    #pragma unroll 1
    for (int t = 0; t < TT; ++t) {
        // ================= layer 0: gate mat-vecs =================
        #pragma unroll
        for (int b = 0; b < NB; ++b) {
            const float* xt = &xbuf[b * TT * II + t * II];
            float ax = bi0;
            #pragma unroll
            for (int k = 0; k < II; ++k) ax = fmaf(wih0[k], xt[k], ax);

            const float4* h4 = (const float4*)h0buf[b];
            float acc[4] = {0.f, 0.f, 0.f, 0.f};
            #pragma unroll
            for (int c = 0; c < HH / 4; ++c) {
                float4 v = h4[c];
                acc[0] = fmaf(whh0[4*c+0], v.x, acc[0]);
                acc[1] = fmaf(whh0[4*c+1], v.y, acc[1]);
                acc[2] = fmaf(whh0[4*c+2], v.z, acc[2]);
                acc[3] = fmaf(whh0[4*c+3], v.w, acc[3]);
            }
            float ah = bh0 + ((acc[0] + acc[1]) + (acc[2] + acc[3]));

            if (wid == 0)      rbuf[b][lane] = fsigm(ax + ah);
            else if (wid == 1) zbuf[b][lane] = fsigm(ax + ah);
            else             { xnS[b] = ax;  hnS[b] = ah; }
        }
        __syncthreads();
        if (wid == 2) {
            #pragma unroll
            for (int b = 0; b < NB; ++b) {
                float r = rbuf[b][lane], z = zbuf[b][lane];
                float n = ftanh(fmaf(r, hnS[b], xnS[b]));
                float h = h0buf[b][lane];
                h0buf[b][lane] = n + z * (h - n);   // (1-z)*n + z*h
            }
        }
        __syncthreads();
        // ================= layer 1: gate mat-vecs =================
        #pragma unroll
        for (int b = 0; b < NB; ++b) {
            const float4* g4 = (const float4*)h0buf[b];   // layer-0 output (this step)
            const float4* h4 = (const float4*)h1buf[b];
            float axA[4] = {0.f, 0.f, 0.f, 0.f};
            float ahA[4] = {0.f, 0.f, 0.f, 0.f};
            #pragma unroll
            for (int c = 0; c < HH / 4; ++c) {
                float4 u = g4[c];
                float4 v = h4[c];
                axA[0] = fmaf(wih1[4*c+0], u.x, axA[0]);
                axA[1] = fmaf(wih1[4*c+1], u.y, axA[1]);
                axA[2] = fmaf(wih1[4*c+2], u.z, axA[2]);
                axA[3] = fmaf(wih1[4*c+3], u.w, axA[3]);
                ahA[0] = fmaf(whh1[4*c+0], v.x, ahA[0]);
                ahA[1] = fmaf(whh1[4*c+1], v.y, ahA[1]);
                ahA[2] = fmaf(whh1[4*c+2], v.z, ahA[2]);
                ahA[3] = fmaf(whh1[4*c+3], v.w, ahA[3]);
            }
            float ax = bi1 + ((axA[0] + axA[1]) + (axA[2] + axA[3]));
            float ah = bh1 + ((ahA[0] + ahA[1]) + (ahA[2] + ahA[3]));

            if (wid == 0)      rbuf[b][lane] = fsigm(ax + ah);
            else if (wid == 1) zbuf[b][lane] = fsigm(ax + ah);
            else             { xnS[b] = ax;  hnS[b] = ah; }
        }
        __syncthreads();
        if (wid == 2) {
            #pragma unroll
            for (int b = 0; b < NB; ++b) {
                float r = rbuf[b][lane], z = zbuf[b][lane];
                float n = ftanh(fmaf(r, hnS[b], xnS[b]));
                float h = h1buf[b][lane];
                h1buf[b][lane] = n + z * (h - n);
            }
        }
        __syncthreads();
    }

    // ---- final FC: out[b] = dot(h1, Wfc) + bfc  (wave w handles batch w)
    if (wid < NB) {
        const int b = wid;
        float p = h1buf[b][lane] * Wfc[lane];
        #pragma unroll
        for (int off = 32; off > 0; off >>= 1) p += __shfl_xor(p, off, 64);
        if (lane == 0) out[b0 + b] = p + bfc[0];
    }
}

extern "C" void kernel_launch(void* const* d_in, const int* in_sizes, int n_in,
                              void* d_out, int out_size, void* d_ws, size_t ws_size,
                              hipStream_t stream)
{
    const float* x    = (const float*)d_in[0];
    const float* Wih0 = (const float*)d_in[1];
    const float* Whh0 = (const float*)d_in[2];
    const float* bih0 = (const float*)d_in[3];
    const float* bhh0 = (const float*)d_in[4];
    const float* Wih1 = (const float*)d_in[5];
    const float* Whh1 = (const float*)d_in[6];
    const float* bih1 = (const float*)d_in[7];
    const float* bhh1 = (const float*)d_in[8];
    const float* Wfc  = (const float*)d_in[9];
    const float* bfc  = (const float*)d_in[10];
    float* out = (float*)d_out;

    dim3 grid(4096 / NB), block(192);
    gru2_fused<<<grid, block, 0, stream>>>(x, Wih0, Whh0, bih0, bhh0,
                                           Wih1, Whh1, bih1, bhh1,
                                           Wfc, bfc, out);
}

// Round 2
// 447.386 us; speedup vs baseline: 5.1013x; 5.1013x over previous
//
#include <hip/hip_runtime.h>
#include <stdint.h>

#define TT 256
#define II 6
#define HH 64
#define MB 16   // batches per block (one 16-wide MFMA N-tile)

typedef __attribute__((ext_vector_type(8))) short short8;
typedef __attribute__((ext_vector_type(4))) float f32x4;

static __device__ __forceinline__ uint32_t bf16_rne(float f){
    uint32_t u = __builtin_bit_cast(uint32_t, f);
    return (u + 0x7fffu + ((u >> 16) & 1u)) >> 16;
}
static __device__ __forceinline__ float bf16_back(uint32_t b){
    return __builtin_bit_cast(float, b << 16);
}
static __device__ __forceinline__ float fsigm(float v){
    float e = __builtin_amdgcn_exp2f(-1.44269504f * v);
    return __builtin_amdgcn_rcpf(1.0f + e);
}
static __device__ __forceinline__ float ftanh(float v){
    v = fminf(20.0f, fmaxf(-20.0f, v));
    float e = __builtin_amdgcn_exp2f(-2.88539008f * v); // exp(-2v)
    return (1.0f - e) * __builtin_amdgcn_rcpf(1.0f + e);
}
static __device__ __forceinline__ short8 mk8(uint32_t a, uint32_t b, uint32_t c, uint32_t d){
    union { uint32_t u[4]; short8 v; } x;
    x.u[0]=a; x.u[1]=b; x.u[2]=c; x.u[3]=d;
    return x.v;
}
static __device__ __forceinline__ short8 ld8(uint4 q){
    union { uint4 q; short8 v; } x;
    x.q = q;
    return x.v;
}

#define MF(C, A, B) C = __builtin_amdgcn_mfma_f32_16x16x32_bf16(A, B, C, 0, 0, 0)
// two MFMAs reconstructing the exact fp32 product:
//  slots i<4 of B hold h_hi, i>=4 hold h_lo (same j per i&3)
//  A pass 1 = {w_hi | w_lo} -> hi*hi + lo*lo ; A pass 2 = {w_lo | w_hi} -> lo*hi + hi*lo
#define ACC2(C, m, cw, HB) \
    MF(C, mk8(Whi[m][cw][0], Whi[m][cw][1], Wlo[m][cw][0], Wlo[m][cw][1]), HB); \
    MF(C, mk8(Wlo[m][cw][0], Wlo[m][cw][1], Whi[m][cw][0], Whi[m][cw][1]), HB)

__global__ __launch_bounds__(256, 1)
void gru2_mfma(const float* __restrict__ x,
               const float* __restrict__ Wih0, const float* __restrict__ Whh0,
               const float* __restrict__ bih0, const float* __restrict__ bhh0,
               const float* __restrict__ Wih1, const float* __restrict__ Whh1,
               const float* __restrict__ bih1, const float* __restrict__ bhh1,
               const float* __restrict__ Wfc,  const float* __restrict__ bfc,
               float* __restrict__ out)
{
    // h exchange buffers: [layer][parity][chunk(=producing wave)][lane] : 16B B-fragments
    __shared__ uint4 hbuf[2][2][4][64];   // 16 KB
    __shared__ float fcpart[256];

    const int tid  = threadIdx.x;
    const int lane = tid & 63;
    const int w    = tid >> 6;     // wave 0..3 : owns gate cols [16w,16w+16) of each gate
    const int c    = lane >> 4;    // k-group 0..3 within wave
    const int r16  = lane & 15;    // A.m / B.n index
    const int b0   = blockIdx.x * MB;

    // zero both parities of both layers
    {
        uint4 z = make_uint4(0u, 0u, 0u, 0u);
        uint4* hb = &hbuf[0][0][0][0];
        hb[tid] = z; hb[tid + 256] = z; hb[tid + 512] = z; hb[tid + 768] = z;
    }

    // ---- weights -> A-fragment registers (hi/lo bf16), once ----
    // tile-matrices: 0..2 Whh0{r,z,n}, 3..5 Wih1{r,z,n}, 6..8 Whh1{r,z,n}
    uint32_t Whi[9][4][2], Wlo[9][4][2];
    {
        const float* Wm[3] = { Whh0, Wih1, Whh1 };
        #pragma unroll
        for (int m = 0; m < 9; ++m){
            const float* rowp = Wm[m / 3] + (size_t)((m % 3) * 64 + w * 16 + r16) * HH;
            #pragma unroll
            for (int cw = 0; cw < 4; ++cw){
                const float* p = rowp + cw * 16 + c * 4;   // j = 16*cw + 4*c + {0..3}
                float v0 = p[0], v1 = p[1], v2 = p[2], v3 = p[3];
                uint32_t h0 = bf16_rne(v0), h1 = bf16_rne(v1), h2 = bf16_rne(v2), h3 = bf16_rne(v3);
                uint32_t l0 = bf16_rne(v0 - bf16_back(h0)), l1 = bf16_rne(v1 - bf16_back(h1));
                uint32_t l2 = bf16_rne(v2 - bf16_back(h2)), l3 = bf16_rne(v3 - bf16_back(h3));
                Whi[m][cw][0] = h0 | (h1 << 16); Whi[m][cw][1] = h2 | (h3 << 16);
                Wlo[m][cw][0] = l0 | (l1 << 16); Wlo[m][cw][1] = l2 | (l3 << 16);
            }
        }
    }

    // Wih0 (192x6) A-fragments: k-slots c0: w_hi (pairs x_hi), c1: w_hi (pairs x_lo),
    // c2: w_lo (pairs x_hi), c3: zero.  Per-lane content depends on its c.
    uint32_t Wx[3][3];
    #pragma unroll
    for (int g = 0; g < 3; ++g){
        const float* rowp = Wih0 + (size_t)(g * 64 + w * 16 + r16) * II;
        float v0 = rowp[0], v1 = rowp[1], v2 = rowp[2], v3 = rowp[3], v4 = rowp[4], v5 = rowp[5];
        uint32_t h0 = bf16_rne(v0), h1 = bf16_rne(v1), h2 = bf16_rne(v2),
                 h3 = bf16_rne(v3), h4 = bf16_rne(v4), h5 = bf16_rne(v5);
        uint32_t a, b2, d;
        if (c == 2){
            uint32_t l0 = bf16_rne(v0 - bf16_back(h0)), l1 = bf16_rne(v1 - bf16_back(h1));
            uint32_t l2 = bf16_rne(v2 - bf16_back(h2)), l3 = bf16_rne(v3 - bf16_back(h3));
            uint32_t l4 = bf16_rne(v4 - bf16_back(h4)), l5 = bf16_rne(v5 - bf16_back(h5));
            a = l0 | (l1 << 16); b2 = l2 | (l3 << 16); d = l4 | (l5 << 16);
        } else if (c == 3){
            a = b2 = d = 0u;
        } else {
            a = h0 | (h1 << 16); b2 = h2 | (h3 << 16); d = h4 | (h5 << 16);
        }
        Wx[g][0] = a; Wx[g][1] = b2; Wx[g][2] = d;
    }

    // biases for this lane's C rows: row = g*64 + w*16 + 4c + q
    const int rq0 = w * 16 + c * 4;
    f32x4 br0, bz0, bxn0, bhn0, br1, bz1, bxn1, bhn1;
    #pragma unroll
    for (int q = 0; q < 4; ++q){
        br0[q]  = bih0[      rq0 + q] + bhh0[      rq0 + q];
        bz0[q]  = bih0[ 64 + rq0 + q] + bhh0[ 64 + rq0 + q];
        bxn0[q] = bih0[128 + rq0 + q];
        bhn0[q] = bhh0[128 + rq0 + q];
        br1[q]  = bih1[      rq0 + q] + bhh1[      rq0 + q];
        bz1[q]  = bih1[ 64 + rq0 + q] + bhh1[ 64 + rq0 + q];
        bxn1[q] = bih1[128 + rq0 + q];
        bhn1[q] = bhh1[128 + rq0 + q];
    }

    f32x4 h0p = {0.f, 0.f, 0.f, 0.f};   // own h slice, layer 0: (j = 16w+4c+q, batch = r16)
    f32x4 h1p = {0.f, 0.f, 0.f, 0.f};

    // x prefetch (row of this lane's batch)
    const float* xrow = x + (size_t)(b0 + r16) * (TT * II);
    float2 xA = *(const float2*)(xrow + 0);
    float2 xB = *(const float2*)(xrow + 2);
    float2 xC = *(const float2*)(xrow + 4);

    __syncthreads();

    #pragma unroll 1
    for (int t = 0; t < TT; ++t){
        const int p = t & 1;

        // ---- x_t B-fragment (hi for c0/c2, lo for c1, zero c3) ----
        float xv0 = xA.x, xv1 = xA.y, xv2 = xB.x, xv3 = xB.y, xv4 = xC.x, xv5 = xC.y;
        uint32_t e0 = bf16_rne(xv0), e1 = bf16_rne(xv1), e2 = bf16_rne(xv2),
                 e3 = bf16_rne(xv3), e4 = bf16_rne(xv4), e5 = bf16_rne(xv5);
        uint32_t xw0, xw1, xw2;
        if (c == 1){
            uint32_t l0 = bf16_rne(xv0 - bf16_back(e0)), l1 = bf16_rne(xv1 - bf16_back(e1));
            uint32_t l2 = bf16_rne(xv2 - bf16_back(e2)), l3 = bf16_rne(xv3 - bf16_back(e3));
            uint32_t l4 = bf16_rne(xv4 - bf16_back(e4)), l5 = bf16_rne(xv5 - bf16_back(e5));
            xw0 = l0 | (l1 << 16); xw1 = l2 | (l3 << 16); xw2 = l4 | (l5 << 16);
        } else if (c == 3){
            xw0 = xw1 = xw2 = 0u;
        } else {
            xw0 = e0 | (e1 << 16); xw1 = e2 | (e3 << 16); xw2 = e4 | (e5 << 16);
        }
        short8 XB = mk8(xw0, xw1, xw2, 0u);

        // prefetch x_{t+1}
        {
            const int tn = (t + 1 < TT) ? (t + 1) : t;
            const float* np = xrow + tn * II;
            xA = *(const float2*)(np + 0);
            xB = *(const float2*)(np + 2);
            xC = *(const float2*)(np + 4);
        }

        // ================= layer 0 =================
        f32x4 Cr = br0, Cz = bz0, Cxn = bxn0, Chn = bhn0;
        MF(Cr,  mk8(Wx[0][0], Wx[0][1], Wx[0][2], 0u), XB);
        MF(Cz,  mk8(Wx[1][0], Wx[1][1], Wx[1][2], 0u), XB);
        MF(Cxn, mk8(Wx[2][0], Wx[2][1], Wx[2][2], 0u), XB);
        #pragma unroll
        for (int cw = 0; cw < 4; ++cw){
            short8 HB = ld8(hbuf[0][p][cw][lane]);
            ACC2(Cr,  0, cw, HB);
            ACC2(Cz,  1, cw, HB);
            ACC2(Chn, 2, cw, HB);
        }
        {
            uint32_t hh[4], ll[4];
            #pragma unroll
            for (int q = 0; q < 4; ++q){
                float rg = fsigm(Cr[q]);
                float zg = fsigm(Cz[q]);
                float ng = ftanh(Cxn[q] + rg * Chn[q]);
                float h  = ng + zg * (h0p[q] - ng);
                h0p[q] = h;
                hh[q] = bf16_rne(h);
                ll[q] = bf16_rne(h - bf16_back(hh[q]));
            }
            hbuf[0][p ^ 1][w][lane] = make_uint4(hh[0] | (hh[1] << 16), hh[2] | (hh[3] << 16),
                                                 ll[0] | (ll[1] << 16), ll[2] | (ll[3] << 16));
        }
        __syncthreads();

        // ================= layer 1 =================
        f32x4 Dr = br1, Dz = bz1, Dxn = bxn1, Dhn = bhn1;
        #pragma unroll
        for (int cw = 0; cw < 4; ++cw){
            short8 HB = ld8(hbuf[0][p ^ 1][cw][lane]);   // h0 (new)
            ACC2(Dr,  3, cw, HB);
            ACC2(Dz,  4, cw, HB);
            ACC2(Dxn, 5, cw, HB);
        }
        #pragma unroll
        for (int cw = 0; cw < 4; ++cw){
            short8 HB = ld8(hbuf[1][p][cw][lane]);       // h1 (prev)
            ACC2(Dr,  6, cw, HB);
            ACC2(Dz,  7, cw, HB);
            ACC2(Dhn, 8, cw, HB);
        }
        {
            uint32_t hh[4], ll[4];
            #pragma unroll
            for (int q = 0; q < 4; ++q){
                float rg = fsigm(Dr[q]);
                float zg = fsigm(Dz[q]);
                float ng = ftanh(Dxn[q] + rg * Dhn[q]);
                float h  = ng + zg * (h1p[q] - ng);
                h1p[q] = h;
                hh[q] = bf16_rne(h);
                ll[q] = bf16_rne(h - bf16_back(hh[q]));
            }
            hbuf[1][p ^ 1][w][lane] = make_uint4(hh[0] | (hh[1] << 16), hh[2] | (hh[3] << 16),
                                                 ll[0] | (ll[1] << 16), ll[2] | (ll[3] << 16));
        }
        __syncthreads();
    }

    // ---- final FC: out[b] = dot(h1_final[b], Wfc) + bfc ----
    {
        float4 wf = *(const float4*)(Wfc + w * 16 + c * 4);
        float pt = h1p[0] * wf.x + h1p[1] * wf.y + h1p[2] * wf.z + h1p[3] * wf.w;
        fcpart[w * 64 + lane] = pt;    // index = (w*4+c)*16 + r16
    }
    __syncthreads();
    if (tid < MB){
        float s = bfc[0];
        #pragma unroll
        for (int u = 0; u < 16; ++u) s += fcpart[u * 16 + tid];
        out[b0 + tid] = s;
    }
}

extern "C" void kernel_launch(void* const* d_in, const int* in_sizes, int n_in,
                              void* d_out, int out_size, void* d_ws, size_t ws_size,
                              hipStream_t stream)
{
    const float* x    = (const float*)d_in[0];
    const float* Wih0 = (const float*)d_in[1];
    const float* Whh0 = (const float*)d_in[2];
    const float* bih0 = (const float*)d_in[3];
    const float* bhh0 = (const float*)d_in[4];
    const float* Wih1 = (const float*)d_in[5];
    const float* Whh1 = (const float*)d_in[6];
    const float* bih1 = (const float*)d_in[7];
    const float* bhh1 = (const float*)d_in[8];
    const float* Wfc  = (const float*)d_in[9];
    const float* bfc  = (const float*)d_in[10];
    float* out = (float*)d_out;

    dim3 grid(4096 / MB), block(256);
    gru2_mfma<<<grid, block, 0, stream>>>(x, Wih0, Whh0, bih0, bhh0,
                                          Wih1, Whh1, bih1, bhh1,
                                          Wfc, bfc, out);
}

// Round 3
// 309.660 us; speedup vs baseline: 7.3702x; 1.4448x over previous
//
#include <hip/hip_runtime.h>
#include <stdint.h>

#define TT 256
#define II 6
#define HH 64
#define MB 16   // batches per block (one 16-wide MFMA N-tile)

typedef __attribute__((ext_vector_type(8))) short short8;
typedef __attribute__((ext_vector_type(4))) float f32x4;

static __device__ __forceinline__ uint32_t bf16_rne(float f){
    uint32_t u = __builtin_bit_cast(uint32_t, f);
    return (u + 0x7fffu + ((u >> 16) & 1u)) >> 16;
}
static __device__ __forceinline__ float bf16_back(uint32_t b){
    return __builtin_bit_cast(float, b << 16);
}
static __device__ __forceinline__ float fsigm(float v){
    float e = __builtin_amdgcn_exp2f(-1.44269504f * v);
    return __builtin_amdgcn_rcpf(1.0f + e);
}
static __device__ __forceinline__ float ftanh(float v){
    v = fminf(20.0f, fmaxf(-20.0f, v));
    float e = __builtin_amdgcn_exp2f(-2.88539008f * v); // exp(-2v)
    return (1.0f - e) * __builtin_amdgcn_rcpf(1.0f + e);
}
static __device__ __forceinline__ short8 mk8(uint32_t a, uint32_t b, uint32_t c, uint32_t d){
    union { uint32_t u[4]; short8 v; } x;
    x.u[0]=a; x.u[1]=b; x.u[2]=c; x.u[3]=d;
    return x.v;
}
static __device__ __forceinline__ short8 ld8(uint4 q){
    union { uint4 q; short8 v; } x;
    x.q = q;
    return x.v;
}

#define MF(C, A, B) C = __builtin_amdgcn_mfma_f32_16x16x32_bf16(A, B, C, 0, 0, 0)

// Exact fp32 product via fixed A = {w_hi | w_lo} and two B variants:
//  B1 = {h_hi | h_lo} -> whi*hhi + wlo*hlo ; B2 = {h_lo | h_hi} -> whi*hlo + wlo*hhi

__global__ __launch_bounds__(512, 2)
void gru2_pipe(const float* __restrict__ x,
               const float* __restrict__ Wih0, const float* __restrict__ Whh0,
               const float* __restrict__ bih0, const float* __restrict__ bhh0,
               const float* __restrict__ Wih1, const float* __restrict__ Whh1,
               const float* __restrict__ bih1, const float* __restrict__ bhh1,
               const float* __restrict__ Wfc,  const float* __restrict__ bfc,
               float* __restrict__ out)
{
    // B-fragment exchange buffers: [parity][chunk(=producing wave)][lane]
    __shared__ uint4 h0buf[2][4][64];   // 8 KB
    __shared__ uint4 h1buf[2][4][64];   // 8 KB
    __shared__ float fcpart[256];

    const int tid  = threadIdx.x;
    const int lane = tid & 63;
    const int wg   = tid >> 6;       // 0..7
    const int isL1 = (wg >= 4);      // waves 4..7 run layer 1 (lagged one tick)
    const int w    = wg & 3;         // gate-column tile within the layer
    const int c    = lane >> 4;      // k-group
    const int r16  = lane & 15;      // batch index within tile
    const int b0   = blockIdx.x * MB;

    {   // zero both parities of both buffers (512 uint4 each... 512 total per buf)
        uint4 zz = make_uint4(0u,0u,0u,0u);
        (&h0buf[0][0][0])[tid] = zz;
        (&h1buf[0][0][0])[tid] = zz;
    }

    // ---- A-fragments (contiguous short8 tuples, built once) ----
    // L0 waves: AW[0..2] = Whh0 {r,z,n}.  L1 waves: AW[0..2]=Wih1, AW[3..5]=Whh1.
    short8 AW[6][4];
    {
        const float* M0 = isL1 ? Wih1 : Whh0;
        #pragma unroll
        for (int m = 0; m < 6; ++m){
            if (m >= 3 && !isL1) continue;
            const float* Wb = (m < 3) ? M0 : Whh1;
            const float* rowp = Wb + (size_t)((m % 3) * 64 + w * 16 + r16) * HH;
            #pragma unroll
            for (int cw = 0; cw < 4; ++cw){
                const float* pp = rowp + cw * 16 + c * 4;
                float v0 = pp[0], v1 = pp[1], v2 = pp[2], v3 = pp[3];
                uint32_t h0 = bf16_rne(v0), h1 = bf16_rne(v1), h2 = bf16_rne(v2), h3 = bf16_rne(v3);
                uint32_t l0 = bf16_rne(v0 - bf16_back(h0)), l1 = bf16_rne(v1 - bf16_back(h1));
                uint32_t l2 = bf16_rne(v2 - bf16_back(h2)), l3 = bf16_rne(v3 - bf16_back(h3));
                AW[m][cw] = mk8(h0 | (h1 << 16), h2 | (h3 << 16),
                                l0 | (l1 << 16), l2 | (l3 << 16));
            }
        }
    }

    // Wih0 (192x6) A-fragments, single-pass hi/lo via k-group assignment:
    // c0: w_hi (pairs x_hi), c1: w_hi (pairs x_lo), c2: w_lo (pairs x_hi), c3: zero
    short8 Ax[3];
    #pragma unroll
    for (int g = 0; g < 3; ++g){
        const float* rowp = Wih0 + (size_t)(g * 64 + w * 16 + r16) * II;
        float v0 = rowp[0], v1 = rowp[1], v2 = rowp[2], v3 = rowp[3], v4 = rowp[4], v5 = rowp[5];
        uint32_t h0 = bf16_rne(v0), h1 = bf16_rne(v1), h2 = bf16_rne(v2),
                 h3 = bf16_rne(v3), h4 = bf16_rne(v4), h5 = bf16_rne(v5);
        uint32_t a, b2, d;
        if (c == 2){
            uint32_t l0 = bf16_rne(v0 - bf16_back(h0)), l1 = bf16_rne(v1 - bf16_back(h1));
            uint32_t l2 = bf16_rne(v2 - bf16_back(h2)), l3 = bf16_rne(v3 - bf16_back(h3));
            uint32_t l4 = bf16_rne(v4 - bf16_back(h4)), l5 = bf16_rne(v5 - bf16_back(h5));
            a = l0 | (l1 << 16); b2 = l2 | (l3 << 16); d = l4 | (l5 << 16);
        } else if (c == 3){
            a = b2 = d = 0u;
        } else {
            a = h0 | (h1 << 16); b2 = h2 | (h3 << 16); d = h4 | (h5 << 16);
        }
        Ax[g] = mk8(a, b2, d, 0u);
    }

    // biases for this lane's C rows: row = g*64 + w*16 + 4c + q  (layer per wave group)
    const float* bi = isL1 ? bih1 : bih0;
    const float* bh = isL1 ? bhh1 : bhh0;
    const int rq0 = w * 16 + c * 4;
    f32x4 Br, Bz, Bxn, Bhn;
    #pragma unroll
    for (int q = 0; q < 4; ++q){
        Br[q]  = bi[      rq0 + q] + bh[      rq0 + q];
        Bz[q]  = bi[ 64 + rq0 + q] + bh[ 64 + rq0 + q];
        Bxn[q] = bi[128 + rq0 + q];
        Bhn[q] = bh[128 + rq0 + q];
    }

    f32x4 hp = {0.f, 0.f, 0.f, 0.f};  // own h slice: (j = 16w+4c+q, batch = r16)

    const float* xrow = x + (size_t)(b0 + r16) * (TT * II);
    float2 xA = make_float2(0.f,0.f), xB = xA, xC = xA;
    if (!isL1){
        xA = *(const float2*)(xrow + 0);
        xB = *(const float2*)(xrow + 2);
        xC = *(const float2*)(xrow + 4);
    }

    __syncthreads();

    // ticks 0..TT: L0 computes h0(tk) for tk<TT; L1 computes h1(tk-1) for tk>=1
    #pragma unroll 1
    for (int tk = 0; tk <= TT; ++tk){
        const int p = tk & 1;
        if (!isL1){
            if (tk < TT){
                // x_t B-fragment (c0/c2: hi, c1: lo, c3: zero)
                float xv0 = xA.x, xv1 = xA.y, xv2 = xB.x, xv3 = xB.y, xv4 = xC.x, xv5 = xC.y;
                uint32_t e0 = bf16_rne(xv0), e1 = bf16_rne(xv1), e2 = bf16_rne(xv2),
                         e3 = bf16_rne(xv3), e4 = bf16_rne(xv4), e5 = bf16_rne(xv5);
                uint32_t xw0, xw1, xw2;
                if (c == 1){
                    uint32_t l0 = bf16_rne(xv0 - bf16_back(e0)), l1 = bf16_rne(xv1 - bf16_back(e1));
                    uint32_t l2 = bf16_rne(xv2 - bf16_back(e2)), l3 = bf16_rne(xv3 - bf16_back(e3));
                    uint32_t l4 = bf16_rne(xv4 - bf16_back(e4)), l5 = bf16_rne(xv5 - bf16_back(e5));
                    xw0 = l0 | (l1 << 16); xw1 = l2 | (l3 << 16); xw2 = l4 | (l5 << 16);
                } else if (c == 3){
                    xw0 = xw1 = xw2 = 0u;
                } else {
                    xw0 = e0 | (e1 << 16); xw1 = e2 | (e3 << 16); xw2 = e4 | (e5 << 16);
                }
                short8 XB = mk8(xw0, xw1, xw2, 0u);
                {   // prefetch x(tk+1)
                    const int tn = (tk + 1 < TT) ? (tk + 1) : tk;
                    const float* np = xrow + tn * II;
                    xA = *(const float2*)(np + 0);
                    xB = *(const float2*)(np + 2);
                    xC = *(const float2*)(np + 4);
                }

                f32x4 Cr = Br, Cz = Bz, Cxn = Bxn, Chn = Bhn;
                MF(Cr,  Ax[0], XB);
                MF(Cz,  Ax[1], XB);
                MF(Cxn, Ax[2], XB);
                #pragma unroll
                for (int cw = 0; cw < 4; ++cw){
                    uint4 qv = h0buf[p][cw][lane];
                    short8 B1 = ld8(qv);
                    short8 B2 = ld8(make_uint4(qv.z, qv.w, qv.x, qv.y));
                    MF(Cr,  AW[0][cw], B1);  MF(Cr,  AW[0][cw], B2);
                    MF(Cz,  AW[1][cw], B1);  MF(Cz,  AW[1][cw], B2);
                    MF(Chn, AW[2][cw], B1);  MF(Chn, AW[2][cw], B2);
                }
                uint32_t hh[4], ll[4];
                #pragma unroll
                for (int q = 0; q < 4; ++q){
                    float rg = fsigm(Cr[q]);
                    float zg = fsigm(Cz[q]);
                    float ng = ftanh(Cxn[q] + rg * Chn[q]);
                    float h2 = ng + zg * (hp[q] - ng);
                    hp[q] = h2;
                    hh[q] = bf16_rne(h2);
                    ll[q] = bf16_rne(h2 - bf16_back(hh[q]));
                }
                h0buf[p ^ 1][w][lane] = make_uint4(hh[0] | (hh[1] << 16), hh[2] | (hh[3] << 16),
                                                   ll[0] | (ll[1] << 16), ll[2] | (ll[3] << 16));
            }
        } else {
            if (tk >= 1){
                f32x4 Cr = Br, Cz = Bz, Cxn = Bxn, Chn = Bhn;
                #pragma unroll
                for (int cw = 0; cw < 4; ++cw){       // Wih1 x h0(tk-1)
                    uint4 qv = h0buf[p][cw][lane];
                    short8 B1 = ld8(qv);
                    short8 B2 = ld8(make_uint4(qv.z, qv.w, qv.x, qv.y));
                    MF(Cr,  AW[0][cw], B1);  MF(Cr,  AW[0][cw], B2);
                    MF(Cz,  AW[1][cw], B1);  MF(Cz,  AW[1][cw], B2);
                    MF(Cxn, AW[2][cw], B1);  MF(Cxn, AW[2][cw], B2);
                }
                #pragma unroll
                for (int cw = 0; cw < 4; ++cw){       // Whh1 x h1(tk-2)
                    uint4 qv = h1buf[p][cw][lane];
                    short8 B1 = ld8(qv);
                    short8 B2 = ld8(make_uint4(qv.z, qv.w, qv.x, qv.y));
                    MF(Cr,  AW[3][cw], B1);  MF(Cr,  AW[3][cw], B2);
                    MF(Cz,  AW[4][cw], B1);  MF(Cz,  AW[4][cw], B2);
                    MF(Chn, AW[5][cw], B1);  MF(Chn, AW[5][cw], B2);
                }
                uint32_t hh[4], ll[4];
                #pragma unroll
                for (int q = 0; q < 4; ++q){
                    float rg = fsigm(Cr[q]);
                    float zg = fsigm(Cz[q]);
                    float ng = ftanh(Cxn[q] + rg * Chn[q]);
                    float h2 = ng + zg * (hp[q] - ng);
                    hp[q] = h2;
                    hh[q] = bf16_rne(h2);
                    ll[q] = bf16_rne(h2 - bf16_back(hh[q]));
                }
                h1buf[p ^ 1][w][lane] = make_uint4(hh[0] | (hh[1] << 16), hh[2] | (hh[3] << 16),
                                                   ll[0] | (ll[1] << 16), ll[2] | (ll[3] << 16));
            }
        }
        __syncthreads();
    }

    // ---- final FC: out[b] = dot(h1_final[b], Wfc) + bfc  (h1 lives in L1 waves' hp)
    if (isL1){
        float4 wf = *(const float4*)(Wfc + w * 16 + c * 4);
        fcpart[(w * 4 + c) * 16 + r16] =
            hp[0] * wf.x + hp[1] * wf.y + hp[2] * wf.z + hp[3] * wf.w;
    }
    __syncthreads();
    if (tid < MB){
        float s = bfc[0];
        #pragma unroll
        for (int u = 0; u < 16; ++u) s += fcpart[u * 16 + tid];
        out[b0 + tid] = s;
    }
}

extern "C" void kernel_launch(void* const* d_in, const int* in_sizes, int n_in,
                              void* d_out, int out_size, void* d_ws, size_t ws_size,
                              hipStream_t stream)
{
    const float* x    = (const float*)d_in[0];
    const float* Wih0 = (const float*)d_in[1];
    const float* Whh0 = (const float*)d_in[2];
    const float* bih0 = (const float*)d_in[3];
    const float* bhh0 = (const float*)d_in[4];
    const float* Wih1 = (const float*)d_in[5];
    const float* Whh1 = (const float*)d_in[6];
    const float* bih1 = (const float*)d_in[7];
    const float* bhh1 = (const float*)d_in[8];
    const float* Wfc  = (const float*)d_in[9];
    const float* bfc  = (const float*)d_in[10];
    float* out = (float*)d_out;

    dim3 grid(4096 / MB), block(512);
    gru2_pipe<<<grid, block, 0, stream>>>(x, Wih0, Whh0, bih0, bhh0,
                                          Wih1, Whh1, bih1, bhh1,
                                          Wfc, bfc, out);
}

// Round 4
// 210.482 us; speedup vs baseline: 10.8430x; 1.4712x over previous
//
#include <hip/hip_runtime.h>
#include <stdint.h>

#define TT 256
#define II 6
#define HH 64
#define MB 16   // batches per block (one 16-wide MFMA N-tile)

typedef __attribute__((ext_vector_type(8))) _Float16 half8;
typedef __attribute__((ext_vector_type(4))) float f32x4;

static __device__ __forceinline__ float fsigm(float v){
    float e = __builtin_amdgcn_exp2f(-1.44269504f * v);
    return __builtin_amdgcn_rcpf(1.0f + e);
}
static __device__ __forceinline__ float ftanh(float v){
    v = fminf(20.0f, fmaxf(-20.0f, v));
    float e = __builtin_amdgcn_exp2f(-2.88539008f * v); // exp(-2v)
    return (1.0f - e) * __builtin_amdgcn_rcpf(1.0f + e);
}
// pack two floats to two fp16 (RNE) in one dword
static __device__ __forceinline__ uint32_t pkh(float a, float b){
    uint16_t ha = __builtin_bit_cast(uint16_t, (_Float16)a);
    uint16_t hb = __builtin_bit_cast(uint16_t, (_Float16)b);
    return (uint32_t)ha | ((uint32_t)hb << 16);
}
static __device__ __forceinline__ half8 mkh8(uint32_t a, uint32_t b, uint32_t c, uint32_t d){
    union { uint32_t u[4]; half8 v; } x;
    x.u[0]=a; x.u[1]=b; x.u[2]=c; x.u[3]=d;
    return x.v;
}
static __device__ __forceinline__ half8 ldh8(uint4 q){
    union { uint4 q; half8 v; } x;
    x.q = q;
    return x.v;
}

#define MF(C, A, B) C = __builtin_amdgcn_mfma_f32_16x16x32_f16(A, B, C, 0, 0, 0)

// Scheme: A = {w_hi(4 elems) | w_lo(4 elems)} fp16 hi/lo (w exact to ~2^-22),
//         B = {h(4 elems) | h(same 4)} duplicated fp16.
// One MFMA per 16 h-elements per C-tile => 4 per C-tile per K=64. Only h carries
// fp16 rounding (rel <= 4.9e-4).

__global__ __launch_bounds__(512, 2)
void gru2_fp16(const float* __restrict__ x,
               const float* __restrict__ Wih0, const float* __restrict__ Whh0,
               const float* __restrict__ bih0, const float* __restrict__ bhh0,
               const float* __restrict__ Wih1, const float* __restrict__ Whh1,
               const float* __restrict__ bih1, const float* __restrict__ bhh1,
               const float* __restrict__ Wfc,  const float* __restrict__ bfc,
               float* __restrict__ out)
{
    // B-fragment exchange buffers: [parity][chunk(=producing wave)][lane]
    // each uint4 is the pre-duplicated fp16 B operand {d0,d1,d0,d1}
    __shared__ uint4 h0buf[2][4][64];   // 8 KB
    __shared__ uint4 h1buf[2][4][64];   // 8 KB
    __shared__ float fcpart[256];

    const int tid  = threadIdx.x;
    const int lane = tid & 63;
    const int wg   = tid >> 6;       // 0..7
    const int isL1 = (wg >= 4);      // waves 4..7 run layer 1 (lagged one tick)
    const int w    = wg & 3;         // gate-column tile within the layer
    const int c    = lane >> 4;      // k-group
    const int r16  = lane & 15;      // batch index within tile
    const int b0   = blockIdx.x * MB;

    {   // zero both parities of both buffers
        uint4 zz = make_uint4(0u,0u,0u,0u);
        (&h0buf[0][0][0])[tid] = zz;
        (&h1buf[0][0][0])[tid] = zz;
    }

    // ---- A-fragments (fp16 hi/lo, contiguous half8 tuples, built once) ----
    // L0 waves: AW[0..2] = Whh0 {r,z,n}.  L1 waves: AW[0..2]=Wih1, AW[3..5]=Whh1.
    half8 AW[6][4];
    {
        const float* M0 = isL1 ? Wih1 : Whh0;
        #pragma unroll
        for (int m = 0; m < 6; ++m){
            if (m >= 3 && !isL1) continue;
            const float* Wb = (m < 3) ? M0 : Whh1;
            const float* rowp = Wb + (size_t)((m % 3) * 64 + w * 16 + r16) * HH;
            #pragma unroll
            for (int cw = 0; cw < 4; ++cw){
                const float* pp = rowp + cw * 16 + c * 4;   // elements 16cw + 4c + {0..3}
                float v0 = pp[0], v1 = pp[1], v2 = pp[2], v3 = pp[3];
                _Float16 h0 = (_Float16)v0, h1 = (_Float16)v1,
                         h2 = (_Float16)v2, h3 = (_Float16)v3;
                float l0 = v0 - (float)h0, l1 = v1 - (float)h1,
                      l2 = v2 - (float)h2, l3 = v3 - (float)h3;
                AW[m][cw] = mkh8(pkh((float)h0, (float)h1), pkh((float)h2, (float)h3),
                                 pkh(l0, l1),               pkh(l2, l3));
            }
        }
    }

    // Wih0 (192x6) A-fragments: c0 covers elems 0..3, c1 covers elems 4,5 (+zeros),
    // c2/c3 zero.  A = {wx_hi | wx_lo}.
    half8 Ax[3];
    #pragma unroll
    for (int g = 0; g < 3; ++g){
        const float* rowp = Wih0 + (size_t)(g * 64 + w * 16 + r16) * II;
        uint32_t a0 = 0u, a1 = 0u, b0_ = 0u, b1_ = 0u;
        if (c == 0){
            float v0 = rowp[0], v1 = rowp[1], v2 = rowp[2], v3 = rowp[3];
            _Float16 h0 = (_Float16)v0, h1 = (_Float16)v1,
                     h2 = (_Float16)v2, h3 = (_Float16)v3;
            a0 = pkh((float)h0, (float)h1); a1 = pkh((float)h2, (float)h3);
            b0_ = pkh(v0 - (float)h0, v1 - (float)h1);
            b1_ = pkh(v2 - (float)h2, v3 - (float)h3);
        } else if (c == 1){
            float v4 = rowp[4], v5 = rowp[5];
            _Float16 h4 = (_Float16)v4, h5 = (_Float16)v5;
            a0 = pkh((float)h4, (float)h5);
            b0_ = pkh(v4 - (float)h4, v5 - (float)h5);
        }
        Ax[g] = mkh8(a0, a1, b0_, b1_);
    }

    // biases for this lane's C rows: row = g*64 + w*16 + 4c + q  (layer per wave group)
    const float* bi = isL1 ? bih1 : bih0;
    const float* bh = isL1 ? bhh1 : bhh0;
    const int rq0 = w * 16 + c * 4;
    f32x4 Br, Bz, Bxn, Bhn;
    #pragma unroll
    for (int q = 0; q < 4; ++q){
        Br[q]  = bi[      rq0 + q] + bh[      rq0 + q];
        Bz[q]  = bi[ 64 + rq0 + q] + bh[ 64 + rq0 + q];
        Bxn[q] = bi[128 + rq0 + q];
        Bhn[q] = bh[128 + rq0 + q];
    }

    f32x4 hp = {0.f, 0.f, 0.f, 0.f};  // own h slice (fp32 carry): (j = 16w+4c+q, batch = r16)

    const float* xrow = x + (size_t)(b0 + r16) * (TT * II);
    float2 xA = make_float2(0.f,0.f), xB = xA, xC = xA;
    if (!isL1){
        xA = *(const float2*)(xrow + 0);
        xB = *(const float2*)(xrow + 2);
        xC = *(const float2*)(xrow + 4);
    }

    __syncthreads();

    // ticks 0..TT: L0 computes h0(tk) for tk<TT; L1 computes h1(tk-1) for tk>=1
    #pragma unroll 1
    for (int tk = 0; tk <= TT; ++tk){
        const int p = tk & 1;
        if (!isL1){
            if (tk < TT){
                // x_t B-fragment: c0 = {x0..x3|x0..x3}, c1 = {x4,x5,0,0|dup}, c2/c3 zero
                uint32_t x01 = 0u, x23 = 0u;
                if (c == 0){
                    x01 = pkh(xA.x, xA.y);
                    x23 = pkh(xB.x, xB.y);
                } else if (c == 1){
                    x01 = pkh(xC.x, xC.y);
                }
                half8 XB = mkh8(x01, x23, x01, x23);
                {   // prefetch x(tk+1)
                    const int tn = (tk + 1 < TT) ? (tk + 1) : tk;
                    const float* np = xrow + tn * II;
                    xA = *(const float2*)(np + 0);
                    xB = *(const float2*)(np + 2);
                    xC = *(const float2*)(np + 4);
                }

                f32x4 Cr = Br, Cz = Bz, Cxn = Bxn, Chn = Bhn;
                __builtin_amdgcn_s_setprio(1);
                MF(Cr,  Ax[0], XB);
                MF(Cz,  Ax[1], XB);
                MF(Cxn, Ax[2], XB);
                #pragma unroll
                for (int cw = 0; cw < 4; ++cw){
                    half8 HB = ldh8(h0buf[p][cw][lane]);
                    MF(Cr,  AW[0][cw], HB);
                    MF(Cz,  AW[1][cw], HB);
                    MF(Chn, AW[2][cw], HB);
                }
                __builtin_amdgcn_s_setprio(0);
                uint32_t d0, d1;
                {
                    float h0n, h1n, h2n, h3n;
                    #pragma unroll
                    for (int q = 0; q < 4; ++q){
                        float rg = fsigm(Cr[q]);
                        float zg = fsigm(Cz[q]);
                        float ng = ftanh(Cxn[q] + rg * Chn[q]);
                        float h2 = ng + zg * (hp[q] - ng);
                        hp[q] = h2;
                        if (q == 0) h0n = h2; else if (q == 1) h1n = h2;
                        else if (q == 2) h2n = h2; else h3n = h2;
                    }
                    d0 = pkh(h0n, h1n);
                    d1 = pkh(h2n, h3n);
                }
                h0buf[p ^ 1][w][lane] = make_uint4(d0, d1, d0, d1);
            }
        } else {
            if (tk >= 1){
                f32x4 Cr = Br, Cz = Bz, Cxn = Bxn, Chn = Bhn;
                __builtin_amdgcn_s_setprio(1);
                #pragma unroll
                for (int cw = 0; cw < 4; ++cw){       // Wih1 x h0(tk-1)
                    half8 HB = ldh8(h0buf[p][cw][lane]);
                    MF(Cr,  AW[0][cw], HB);
                    MF(Cz,  AW[1][cw], HB);
                    MF(Cxn, AW[2][cw], HB);
                }
                #pragma unroll
                for (int cw = 0; cw < 4; ++cw){       // Whh1 x h1(tk-2)
                    half8 HB = ldh8(h1buf[p][cw][lane]);
                    MF(Cr,  AW[3][cw], HB);
                    MF(Cz,  AW[4][cw], HB);
                    MF(Chn, AW[5][cw], HB);
                }
                __builtin_amdgcn_s_setprio(0);
                uint32_t d0, d1;
                {
                    float h0n, h1n, h2n, h3n;
                    #pragma unroll
                    for (int q = 0; q < 4; ++q){
                        float rg = fsigm(Cr[q]);
                        float zg = fsigm(Cz[q]);
                        float ng = ftanh(Cxn[q] + rg * Chn[q]);
                        float h2 = ng + zg * (hp[q] - ng);
                        hp[q] = h2;
                        if (q == 0) h0n = h2; else if (q == 1) h1n = h2;
                        else if (q == 2) h2n = h2; else h3n = h2;
                    }
                    d0 = pkh(h0n, h1n);
                    d1 = pkh(h2n, h3n);
                }
                h1buf[p ^ 1][w][lane] = make_uint4(d0, d1, d0, d1);
            }
        }
        __syncthreads();
    }

    // ---- final FC: out[b] = dot(h1_final[b], Wfc) + bfc  (h1 lives in L1 waves' hp)
    if (isL1){
        float4 wf = *(const float4*)(Wfc + w * 16 + c * 4);
        fcpart[(w * 4 + c) * 16 + r16] =
            hp[0] * wf.x + hp[1] * wf.y + hp[2] * wf.z + hp[3] * wf.w;
    }
    __syncthreads();
    if (tid < MB){
        float s = bfc[0];
        #pragma unroll
        for (int u = 0; u < 16; ++u) s += fcpart[u * 16 + tid];
        out[b0 + tid] = s;
    }
}

extern "C" void kernel_launch(void* const* d_in, const int* in_sizes, int n_in,
                              void* d_out, int out_size, void* d_ws, size_t ws_size,
                              hipStream_t stream)
{
    const float* x    = (const float*)d_in[0];
    const float* Wih0 = (const float*)d_in[1];
    const float* Whh0 = (const float*)d_in[2];
    const float* bih0 = (const float*)d_in[3];
    const float* bhh0 = (const float*)d_in[4];
    const float* Wih1 = (const float*)d_in[5];
    const float* Whh1 = (const float*)d_in[6];
    const float* bih1 = (const float*)d_in[7];
    const float* bhh1 = (const float*)d_in[8];
    const float* Wfc  = (const float*)d_in[9];
    const float* bfc  = (const float*)d_in[10];
    float* out = (float*)d_out;

    dim3 grid(4096 / MB), block(512);
    gru2_fp16<<<grid, block, 0, stream>>>(x, Wih0, Whh0, bih0, bhh0,
                                          Wih1, Whh1, bih1, bhh1,
                                          Wfc, bfc, out);
}

// Round 5
// 175.723 us; speedup vs baseline: 12.9878x; 1.1978x over previous
//
#include <hip/hip_runtime.h>
#include <stdint.h>

#define TT 256
#define II 6
#define HH 64
#define MB 16   // batches per block (one 16-wide MFMA N-tile)

typedef __attribute__((ext_vector_type(8))) _Float16 half8;
typedef __attribute__((ext_vector_type(4))) float f32x4;

// pack two floats to two fp16 (RNE) in one dword
static __device__ __forceinline__ uint32_t pkh(float a, float b){
    uint16_t ha = __builtin_bit_cast(uint16_t, (_Float16)a);
    uint16_t hb = __builtin_bit_cast(uint16_t, (_Float16)b);
    return (uint32_t)ha | ((uint32_t)hb << 16);
}
static __device__ __forceinline__ half8 mkh8(uint32_t a, uint32_t b, uint32_t c, uint32_t d){
    union { uint32_t u[4]; half8 v; } x;
    x.u[0]=a; x.u[1]=b; x.u[2]=c; x.u[3]=d;
    return x.v;
}
static __device__ __forceinline__ half8 ldq(const uint32_t* p){
    union { uint4 q; half8 v; } x;
    x.q = *(const uint4*)p;          // 16B-aligned by construction
    return x.v;
}

#define MF(C, A, B) C = __builtin_amdgcn_mfma_f32_16x16x32_f16(A, B, C, 0, 0, 0)

// gate math: paired-rcp sigmoids + tanh; returns packed fp16 h pair, updates fp32 carry
static __device__ __forceinline__ uint2 gates(const f32x4& Cr, const f32x4& Cz,
                                              const f32x4& Cxn, const f32x4& Chn,
                                              f32x4& hp)
{
    float hn[4];
    #pragma unroll
    for (int q = 0; q < 4; ++q){
        float pa = 1.0f + __builtin_amdgcn_exp2f(-1.44269504f * Cr[q]);  // 1/r
        float pb = 1.0f + __builtin_amdgcn_exp2f(-1.44269504f * Cz[q]);  // 1/z
        float u  = __builtin_amdgcn_rcpf(pa * pb);
        float rg = u * pb;
        float zg = u * pa;
        float v  = Cxn[q] + rg * Chn[q];
        v = fminf(20.0f, fmaxf(-20.0f, v));
        float e  = __builtin_amdgcn_exp2f(-2.88539008f * v);             // exp(-2v)
        float ng = (1.0f - e) * __builtin_amdgcn_rcpf(1.0f + e);
        float h2 = ng + zg * (hp[q] - ng);
        hp[q] = h2;
        hn[q] = h2;
    }
    return make_uint2(pkh(hn[0], hn[1]), pkh(hn[2], hn[3]));
}

// Single-fp16 scheme: A = full W row slice (8 fp16 per lane, real K=32 per MFMA),
// B = h fp16 (8 per lane). Per gate per K=64 matvec: 2 MFMA.
// h exchange: linear LDS [batch][36 dwords] (pad 36 => 2-way conflicts max = free).

__global__ __launch_bounds__(512, 2)
void gru2_v5(const float* __restrict__ x,
             const float* __restrict__ Wih0, const float* __restrict__ Whh0,
             const float* __restrict__ bih0, const float* __restrict__ bhh0,
             const float* __restrict__ Wih1, const float* __restrict__ Whh1,
             const float* __restrict__ bih1, const float* __restrict__ bhh1,
             const float* __restrict__ Wfc,  const float* __restrict__ bfc,
             float* __restrict__ out)
{
    __shared__ uint2    xtA[TT][16];          // {x01,x23} fp16 pairs  (32 KB)
    __shared__ uint32_t xtB[TT][16];          // {x45}                 (16 KB)
    __shared__ uint32_t h0buf[2][16][36];     // [parity][batch][h/2 dwords+pad] 4.5 KB
    __shared__ uint32_t h1buf[2][16][36];     // 4.5 KB
    __shared__ float    fcpart[256];

    const int tid  = threadIdx.x;
    const int lane = tid & 63;
    const int wg   = tid >> 6;       // 0..7
    const int isL1 = (wg >= 4);      // waves 4..7 run layer 1 (lagged one tick)
    const int w    = wg & 3;         // 16-row tile within each gate
    const int c    = lane >> 4;      // k-group (A/B) and C row-group
    const int r16  = lane & 15;      // batch col (B.n / C.n) and A row
    const int b0   = blockIdx.x * MB;

    // ---- prologue: pre-pack x into LDS fp16 tables (coalesced-ish) ----
    for (int e = tid; e < TT * 16; e += 512){
        const int t = e & 255, b = e >> 8;
        const float* xp = x + ((size_t)(b0 + b) * TT + t) * II;
        float2 a  = *(const float2*)(xp + 0);
        float2 bb = *(const float2*)(xp + 2);
        float2 cc = *(const float2*)(xp + 4);
        xtA[t][b] = make_uint2(pkh(a.x, a.y), pkh(bb.x, bb.y));
        xtB[t][b] = pkh(cc.x, cc.y);
    }
    for (int i = tid; i < 2 * 16 * 36; i += 512){
        (&h0buf[0][0][0])[i] = 0u;
        (&h1buf[0][0][0])[i] = 0u;
    }

    // ---- A-fragments: full-row fp16, 8 elems/lane/chunk, built once ----
    // L0 waves: AW[0..2] = Whh0 {r,z,n} (2 chunks).  L1: AW[0..2]=Wih1, AW[3..5]=Whh1.
    half8 AW[6][2];
    {
        const float* M0 = isL1 ? Wih1 : Whh0;
        #pragma unroll
        for (int m = 0; m < 6; ++m){
            if (m >= 3 && !isL1) continue;
            const float* Wb = (m < 3) ? M0 : Whh1;
            const float* rowp = Wb + (size_t)((m % 3) * 64 + w * 16 + r16) * HH;
            #pragma unroll
            for (int cw = 0; cw < 2; ++cw){
                const float* pp = rowp + cw * 32 + c * 8;   // k = 32cw + 8c + {0..7}
                AW[m][cw] = mkh8(pkh(pp[0], pp[1]), pkh(pp[2], pp[3]),
                                 pkh(pp[4], pp[5]), pkh(pp[6], pp[7]));
            }
        }
    }

    // Wih0 (192x6): only k=0..5 live => only c==0 lanes carry data
    half8 Ax[3];
    #pragma unroll
    for (int g = 0; g < 3; ++g){
        if (c == 0){
            const float* rowp = Wih0 + (size_t)(g * 64 + w * 16 + r16) * II;
            Ax[g] = mkh8(pkh(rowp[0], rowp[1]), pkh(rowp[2], rowp[3]),
                         pkh(rowp[4], rowp[5]), 0u);
        } else {
            Ax[g] = mkh8(0u, 0u, 0u, 0u);
        }
    }

    // biases for this lane's C rows: row = g*64 + w*16 + 4c + q
    const float* bi = isL1 ? bih1 : bih0;
    const float* bh = isL1 ? bhh1 : bhh0;
    const int rq0 = w * 16 + c * 4;
    f32x4 Br, Bz, Bxn, Bhn;
    #pragma unroll
    for (int q = 0; q < 4; ++q){
        Br[q]  = bi[      rq0 + q] + bh[      rq0 + q];
        Bz[q]  = bi[ 64 + rq0 + q] + bh[ 64 + rq0 + q];
        Bxn[q] = bi[128 + rq0 + q];
        Bhn[q] = bh[128 + rq0 + q];
    }

    f32x4 hp = {0.f, 0.f, 0.f, 0.f};   // fp32 carry of own h slice (j=16w+4c+q, batch r16)

    __syncthreads();

    // ticks 0..TT: L0 computes h0(tk) for tk<TT; L1 computes h1(tk-1) for tk>=1
    #pragma unroll 1
    for (int tk = 0; tk <= TT; ++tk){
        const int p = tk & 1;
        if (!isL1){
            if (tk < TT){
                half8 XB;
                if (c == 0){
                    uint2 xa = xtA[tk][r16];
                    XB = mkh8(xa.x, xa.y, xtB[tk][r16], 0u);
                } else {
                    XB = mkh8(0u, 0u, 0u, 0u);
                }
                f32x4 Cr = Br, Cz = Bz, Cxn = Bxn, Chn = Bhn;
                __builtin_amdgcn_s_setprio(1);
                MF(Cr,  Ax[0], XB);
                MF(Cz,  Ax[1], XB);
                MF(Cxn, Ax[2], XB);
                #pragma unroll
                for (int cw = 0; cw < 2; ++cw){
                    half8 HB = ldq(&h0buf[p][r16][16 * cw + 4 * c]);
                    MF(Cr,  AW[0][cw], HB);
                    MF(Cz,  AW[1][cw], HB);
                    MF(Chn, AW[2][cw], HB);
                }
                __builtin_amdgcn_s_setprio(0);
                uint2 d = gates(Cr, Cz, Cxn, Chn, hp);
                *(uint2*)&h0buf[p ^ 1][r16][8 * w + 2 * c] = d;
            }
        } else {
            if (tk >= 1){
                f32x4 Cr = Br, Cz = Bz, Cxn = Bxn, Chn = Bhn;
                __builtin_amdgcn_s_setprio(1);
                #pragma unroll
                for (int cw = 0; cw < 2; ++cw){        // Wih1 x h0(tk-1)
                    half8 HB = ldq(&h0buf[p][r16][16 * cw + 4 * c]);
                    MF(Cr,  AW[0][cw], HB);
                    MF(Cz,  AW[1][cw], HB);
                    MF(Cxn, AW[2][cw], HB);
                }
                #pragma unroll
                for (int cw = 0; cw < 2; ++cw){        // Whh1 x h1(tk-2)
                    half8 HB = ldq(&h1buf[p][r16][16 * cw + 4 * c]);
                    MF(Cr,  AW[3][cw], HB);
                    MF(Cz,  AW[4][cw], HB);
                    MF(Chn, AW[5][cw], HB);
                }
                __builtin_amdgcn_s_setprio(0);
                uint2 d = gates(Cr, Cz, Cxn, Chn, hp);
                *(uint2*)&h1buf[p ^ 1][r16][8 * w + 2 * c] = d;
            }
        }
        __syncthreads();
    }

    // ---- final FC: out[b] = dot(h1_final[b], Wfc) + bfc  (h1 lives in L1 waves' hp)
    if (isL1){
        float4 wf = *(const float4*)(Wfc + w * 16 + c * 4);
        fcpart[(w * 4 + c) * 16 + r16] =
            hp[0] * wf.x + hp[1] * wf.y + hp[2] * wf.z + hp[3] * wf.w;
    }
    __syncthreads();
    if (tid < MB){
        float s = bfc[0];
        #pragma unroll
        for (int u = 0; u < 16; ++u) s += fcpart[u * 16 + tid];
        out[b0 + tid] = s;
    }
}

extern "C" void kernel_launch(void* const* d_in, const int* in_sizes, int n_in,
                              void* d_out, int out_size, void* d_ws, size_t ws_size,
                              hipStream_t stream)
{
    const float* x    = (const float*)d_in[0];
    const float* Wih0 = (const float*)d_in[1];
    const float* Whh0 = (const float*)d_in[2];
    const float* bih0 = (const float*)d_in[3];
    const float* bhh0 = (const float*)d_in[4];
    const float* Wih1 = (const float*)d_in[5];
    const float* Whh1 = (const float*)d_in[6];
    const float* bih1 = (const float*)d_in[7];
    const float* bhh1 = (const float*)d_in[8];
    const float* Wfc  = (const float*)d_in[9];
    const float* bfc  = (const float*)d_in[10];
    float* out = (float*)d_out;

    dim3 grid(4096 / MB), block(512);
    gru2_v5<<<grid, block, 0, stream>>>(x, Wih0, Whh0, bih0, bhh0,
                                        Wih1, Whh1, bih1, bhh1,
                                        Wfc, bfc, out);
}

// Round 6
// 143.058 us; speedup vs baseline: 15.9533x; 1.2283x over previous
//
#include <hip/hip_runtime.h>
#include <stdint.h>

#define TT 256
#define II 6
#define HH 64
#define MB 16   // batches per block (one 16-wide MFMA N-tile)

typedef __attribute__((ext_vector_type(8))) _Float16 half8;
typedef __attribute__((ext_vector_type(4))) float f32x4;

#define K_LOG2E  1.44269504f
#define K_2LOG2E 2.88539008f

// pack two floats to two fp16 (RNE) in one dword
static __device__ __forceinline__ uint32_t pkh(float a, float b){
    uint16_t ha = __builtin_bit_cast(uint16_t, (_Float16)a);
    uint16_t hb = __builtin_bit_cast(uint16_t, (_Float16)b);
    return (uint32_t)ha | ((uint32_t)hb << 16);
}
static __device__ __forceinline__ half8 mkh8(uint32_t a, uint32_t b, uint32_t c, uint32_t d){
    union { uint32_t u[4]; half8 v; } x;
    x.u[0]=a; x.u[1]=b; x.u[2]=c; x.u[3]=d;
    return x.v;
}
static __device__ __forceinline__ half8 ldq(const uint32_t* p){
    union { uint4 q; half8 v; } x;
    x.q = *(const uint4*)p;
    return x.v;
}

#define MF(C, A, B) C = __builtin_amdgcn_mfma_f32_16x16x32_f16(A, B, C, 0, 0, 0)

// Gate fusion. Pre-activations arrive PRE-SCALED: r,z rows by log2e; n rows by
// 2*log2e. So sigma(a) = 1/(1+exp2(-Cr)) and tanh(v) = (1-exp2(-v'))/(1+exp2(-v')).
// No clamp needed: |v'| <= ~40 << 126 (weights |w|<=0.125, |h|<=1, |x|<~6).
static __device__ __forceinline__ uint2 gates(const f32x4& Cr, const f32x4& Cz,
                                              const f32x4& Cxn, const f32x4& Chn,
                                              f32x4& hp)
{
    float hn[4];
    #pragma unroll
    for (int q = 0; q < 4; ++q){
        float er = __builtin_amdgcn_exp2f(-Cr[q]);
        float ez = __builtin_amdgcn_exp2f(-Cz[q]);
        float pa = 1.0f + er, pb = 1.0f + ez;
        float u  = __builtin_amdgcn_rcpf(pa * pb);
        float rg = u * pb;                      // sigma(r)
        float zg = u * pa;                      // sigma(z)
        float v  = Cxn[q] + rg * Chn[q];        // scaled by 2*log2e
        float e  = __builtin_amdgcn_exp2f(-v);
        float ng = (1.0f - e) * __builtin_amdgcn_rcpf(1.0f + e);
        float h2 = ng + zg * (hp[q] - ng);
        hp[q] = h2;
        hn[q] = h2;
    }
    return make_uint2(pkh(hn[0], hn[1]), pkh(hn[2], hn[3]));
}

__global__ __launch_bounds__(512, 2)
void gru2_v6(const float* __restrict__ x,
             const float* __restrict__ Wih0, const float* __restrict__ Whh0,
             const float* __restrict__ bih0, const float* __restrict__ bhh0,
             const float* __restrict__ Wih1, const float* __restrict__ Whh1,
             const float* __restrict__ bih1, const float* __restrict__ bhh1,
             const float* __restrict__ Wfc,  const float* __restrict__ bfc,
             float* __restrict__ out)
{
    __shared__ uint2    xtA[TT][16];          // {x01,x23} fp16 pairs, index rotated by t
    __shared__ uint32_t xtB[TT][16];          // {x45}, same rotation
    __shared__ uint32_t h0buf[2][16][36];     // [parity][batch][h/2 dwords + pad]
    __shared__ uint32_t h1buf[2][16][36];
    __shared__ float    fcpart[256];

    const int tid  = threadIdx.x;
    const int lane = tid & 63;
    const int wg   = tid >> 6;       // 0..7
    const int isL1 = (wg >= 4);      // waves 4..7 run layer 1 (lagged one tick)
    const int w    = wg & 3;         // 16-row tile within each gate
    const int c    = lane >> 4;      // k-group / C row-group
    const int r16  = lane & 15;      // batch col
    const int b0   = blockIdx.x * MB;

    // ---- prologue: pre-pack x into LDS fp16 tables (bank-rotated writes) ----
    for (int e = tid; e < TT * 16; e += 512){
        const int t = e & 255, b = e >> 8;
        const int bi_ = (b + t) & 15;         // rotation: writes <=2-way conflict
        const float* xp = x + ((size_t)(b0 + b) * TT + t) * II;
        float2 a  = *(const float2*)(xp + 0);
        float2 bb = *(const float2*)(xp + 2);
        float2 cc = *(const float2*)(xp + 4);
        xtA[t][bi_] = make_uint2(pkh(a.x, a.y), pkh(bb.x, bb.y));
        xtB[t][bi_] = pkh(cc.x, cc.y);
    }
    for (int i = tid; i < 2 * 16 * 36; i += 512){
        (&h0buf[0][0][0])[i] = 0u;
        (&h1buf[0][0][0])[i] = 0u;
    }

    // ---- A-fragments: fp16, pre-scaled by {log2e, log2e, 2log2e} per gate ----
    // L0 waves: AW[0..2] = Whh0 {r,z,n}.  L1: AW[0..2]=Wih1, AW[3..5]=Whh1.
    const float gsc[3] = { K_LOG2E, K_LOG2E, K_2LOG2E };
    half8 AW[6][2];
    {
        const float* M0 = isL1 ? Wih1 : Whh0;
        #pragma unroll
        for (int m = 0; m < 6; ++m){
            if (m >= 3 && !isL1) continue;
            const float* Wb = (m < 3) ? M0 : Whh1;
            const float s = gsc[m % 3];
            const float* rowp = Wb + (size_t)((m % 3) * 64 + w * 16 + r16) * HH;
            #pragma unroll
            for (int cw = 0; cw < 2; ++cw){
                const float* pp = rowp + cw * 32 + c * 8;
                AW[m][cw] = mkh8(pkh(s*pp[0], s*pp[1]), pkh(s*pp[2], s*pp[3]),
                                 pkh(s*pp[4], s*pp[5]), pkh(s*pp[6], s*pp[7]));
            }
        }
    }

    // Wih0 (192x6): only k=0..5 live => only c==0 lanes carry data (others zero;
    // B-side garbage then multiplies A=0).
    half8 Ax[3];
    #pragma unroll
    for (int g = 0; g < 3; ++g){
        if (c == 0){
            const float s = gsc[g];
            const float* rowp = Wih0 + (size_t)(g * 64 + w * 16 + r16) * II;
            Ax[g] = mkh8(pkh(s*rowp[0], s*rowp[1]), pkh(s*rowp[2], s*rowp[3]),
                         pkh(s*rowp[4], s*rowp[5]), 0u);
        } else {
            Ax[g] = mkh8(0u, 0u, 0u, 0u);
        }
    }

    // biases, pre-scaled likewise: row = g*64 + w*16 + 4c + q
    const float* bi = isL1 ? bih1 : bih0;
    const float* bh = isL1 ? bhh1 : bhh0;
    const int rq0 = w * 16 + c * 4;
    f32x4 Br, Bz, Bxn, Bhn;
    #pragma unroll
    for (int q = 0; q < 4; ++q){
        Br[q]  = K_LOG2E  * (bi[      rq0 + q] + bh[      rq0 + q]);
        Bz[q]  = K_LOG2E  * (bi[ 64 + rq0 + q] + bh[ 64 + rq0 + q]);
        Bxn[q] = K_2LOG2E *  bi[128 + rq0 + q];
        Bhn[q] = K_2LOG2E *  bh[128 + rq0 + q];
    }

    f32x4 hp = {0.f, 0.f, 0.f, 0.f};   // fp32 carry of own h slice (TRUE h, unscaled)

    // hoisted per-parity LDS pointers (constexpr-indexed in TICK)
    const uint32_t* rd0p[2] = { &h0buf[0][r16][4*c], &h0buf[1][r16][4*c] };
    const uint32_t* rd1p[2] = { &h1buf[0][r16][4*c], &h1buf[1][r16][4*c] };
    uint2* wr0p[2] = { (uint2*)&h0buf[0][r16][8*w + 2*c], (uint2*)&h0buf[1][r16][8*w + 2*c] };
    uint2* wr1p[2] = { (uint2*)&h1buf[0][r16][8*w + 2*c], (uint2*)&h1buf[1][r16][8*w + 2*c] };

    __syncthreads();

#define TICK(P, D0, D1, TK) do {                                               \
    if (!isL1) { if (D0) {                                                     \
        const int xi = ((r16 + (TK)) & 15);                                    \
        uint2 xa = xtA[(TK)][xi];                                              \
        uint32_t xb = xtB[(TK)][xi];                                           \
        half8 XB = mkh8(xa.x, xa.y, xb, 0u);                                   \
        f32x4 Cr = Br, Cz = Bz, Cxn = Bxn, Chn = Bhn;                          \
        __builtin_amdgcn_s_setprio(1);                                         \
        MF(Cr,  Ax[0], XB);  MF(Cz,  Ax[1], XB);  MF(Cxn, Ax[2], XB);          \
        { half8 HB = ldq(rd0p[P]);                                             \
          MF(Cr, AW[0][0], HB); MF(Cz, AW[1][0], HB); MF(Chn, AW[2][0], HB); } \
        { half8 HB = ldq(rd0p[P] + 16);                                        \
          MF(Cr, AW[0][1], HB); MF(Cz, AW[1][1], HB); MF(Chn, AW[2][1], HB); } \
        __builtin_amdgcn_s_setprio(0);                                         \
        uint2 d = gates(Cr, Cz, Cxn, Chn, hp);                                 \
        *wr0p[(P) ^ 1] = d;                                                    \
    } } else { if (D1) {                                                       \
        f32x4 Cr = Br, Cz = Bz, Cxn = Bxn, Chn = Bhn;                          \
        __builtin_amdgcn_s_setprio(1);                                         \
        { half8 HB = ldq(rd0p[P]);                                             \
          MF(Cr, AW[0][0], HB); MF(Cz, AW[1][0], HB); MF(Cxn, AW[2][0], HB); } \
        { half8 HB = ldq(rd0p[P] + 16);                                        \
          MF(Cr, AW[0][1], HB); MF(Cz, AW[1][1], HB); MF(Cxn, AW[2][1], HB); } \
        { half8 HB = ldq(rd1p[P]);                                             \
          MF(Cr, AW[3][0], HB); MF(Cz, AW[4][0], HB); MF(Chn, AW[5][0], HB); } \
        { half8 HB = ldq(rd1p[P] + 16);                                        \
          MF(Cr, AW[3][1], HB); MF(Cz, AW[4][1], HB); MF(Chn, AW[5][1], HB); } \
        __builtin_amdgcn_s_setprio(0);                                         \
        uint2 d = gates(Cr, Cz, Cxn, Chn, hp);                                 \
        *wr1p[(P) ^ 1] = d;                                                    \
    } }                                                                        \
} while (0)

    // tick 0: L0 only (parity 0)
    TICK(0, true, false, 0);
    __syncthreads();
    // ticks 1..254 in parity pairs
    #pragma unroll 1
    for (int tk = 1; tk < 255; tk += 2){
        TICK(1, true, true, tk);
        __syncthreads();
        TICK(0, true, true, tk + 1);
        __syncthreads();
    }
    // tick 255 (parity 1, both layers)
    TICK(1, true, true, 255);
    __syncthreads();
    // tick 256: L1 only (parity 0)
    TICK(0, false, true, 256);

#undef TICK

    // ---- final FC: out[b] = dot(h1_final[b], Wfc) + bfc  (h1 lives in L1 waves' hp)
    if (isL1){
        float4 wf = *(const float4*)(Wfc + w * 16 + c * 4);
        fcpart[(w * 4 + c) * 16 + r16] =
            hp[0] * wf.x + hp[1] * wf.y + hp[2] * wf.z + hp[3] * wf.w;
    }
    __syncthreads();
    if (tid < MB){
        float s = bfc[0];
        #pragma unroll
        for (int u = 0; u < 16; ++u) s += fcpart[u * 16 + tid];
        out[b0 + tid] = s;
    }
}

extern "C" void kernel_launch(void* const* d_in, const int* in_sizes, int n_in,
                              void* d_out, int out_size, void* d_ws, size_t ws_size,
                              hipStream_t stream)
{
    const float* x    = (const float*)d_in[0];
    const float* Wih0 = (const float*)d_in[1];
    const float* Whh0 = (const float*)d_in[2];
    const float* bih0 = (const float*)d_in[3];
    const float* bhh0 = (const float*)d_in[4];
    const float* Wih1 = (const float*)d_in[5];
    const float* Whh1 = (const float*)d_in[6];
    const float* bih1 = (const float*)d_in[7];
    const float* bhh1 = (const float*)d_in[8];
    const float* Wfc  = (const float*)d_in[9];
    const float* bfc  = (const float*)d_in[10];
    float* out = (float*)d_out;

    dim3 grid(4096 / MB), block(512);
    gru2_v6<<<grid, block, 0, stream>>>(x, Wih0, Whh0, bih0, bhh0,
                                        Wih1, Whh1, bih1, bhh1,
                                        Wfc, bfc, out);
}

// Round 7
// 142.338 us; speedup vs baseline: 16.0341x; 1.0051x over previous
//
#include <hip/hip_runtime.h>
#include <stdint.h>

#define TT 256
#define II 6
#define HH 64
#define MB 16   // batches per block (one 16-wide MFMA N-tile)

typedef __attribute__((ext_vector_type(8))) _Float16 half8;
typedef __attribute__((ext_vector_type(4))) float f32x4;

#define K_LOG2E  1.44269504f
#define K_2LOG2E 2.88539008f

// RNE pack (init-time only)
static __device__ __forceinline__ uint32_t pkh(float a, float b){
    uint16_t ha = __builtin_bit_cast(uint16_t, (_Float16)a);
    uint16_t hb = __builtin_bit_cast(uint16_t, (_Float16)b);
    return (uint32_t)ha | ((uint32_t)hb << 16);
}
// single-instruction packed cvt (RTZ) for the hot path
static __device__ __forceinline__ uint32_t pkrtz(float a, float b){
    return __builtin_bit_cast(uint32_t, __builtin_amdgcn_cvt_pkrtz(a, b));
}
static __device__ __forceinline__ half8 mkh8(uint32_t a, uint32_t b, uint32_t c, uint32_t d){
    union { uint32_t u[4]; half8 v; } x;
    x.u[0]=a; x.u[1]=b; x.u[2]=c; x.u[3]=d;
    return x.v;
}
static __device__ __forceinline__ half8 ldq(const uint32_t* p){
    union { uint4 q; half8 v; } x;
    x.q = *(const uint4*)p;
    return x.v;
}

#define MF(C, A, B) C = __builtin_amdgcn_mfma_f32_16x16x32_f16(A, B, C, 0, 0, 0)

// Pre-activations arrive pre-scaled (r,z by log2e; n rows by 2log2e), so
// sigma(a)=1/(1+exp2(-C)) and tanh(v)=(1-exp2(-v'))/(1+exp2(-v')); no clamp
// needed (|v'| <= ~40 << 126).
static __device__ __forceinline__ uint2 gates(const f32x4& Cr, const f32x4& Cz,
                                              const f32x4& Cxn, const f32x4& Chn,
                                              f32x4& hp)
{
    float hn[4];
    #pragma unroll
    for (int q = 0; q < 4; ++q){
        float er = __builtin_amdgcn_exp2f(-Cr[q]);
        float ez = __builtin_amdgcn_exp2f(-Cz[q]);
        float pa = 1.0f + er, pb = 1.0f + ez;
        float u  = __builtin_amdgcn_rcpf(pa * pb);
        float rg = u * pb;                      // sigma(r)
        float zg = u * pa;                      // sigma(z)
        float v  = Cxn[q] + rg * Chn[q];
        float e  = __builtin_amdgcn_exp2f(-v);
        float ng = (1.0f - e) * __builtin_amdgcn_rcpf(1.0f + e);
        float h2 = ng + zg * (hp[q] - ng);
        hp[q] = h2; hn[q] = h2;
    }
    return make_uint2(pkrtz(hn[0], hn[1]), pkrtz(hn[2], hn[3]));
}

__global__ __launch_bounds__(512, 2)
void gru2_v7(const float* __restrict__ x,
             const float* __restrict__ Wih0, const float* __restrict__ Whh0,
             const float* __restrict__ bih0, const float* __restrict__ bhh0,
             const float* __restrict__ Wih1, const float* __restrict__ Whh1,
             const float* __restrict__ bih1, const float* __restrict__ bhh1,
             const float* __restrict__ Wfc,  const float* __restrict__ bfc,
             float* __restrict__ out)
{
    __shared__ uint32_t h0buf[2][MB][36];   // [parity][batch][h/2 dwords + pad]
    __shared__ uint32_t h1buf[2][MB][36];
    __shared__ float    fcpart[16][MB];

    const int tid  = threadIdx.x;
    const int lane = tid & 63;
    const int wg   = tid >> 6;       // 0..7
    const int isL1 = (wg >= 4);      // waves 4..7 run layer 1 (lagged one tick)
    const int w    = wg & 3;         // 16-row tile within each gate
    const int c    = lane >> 4;      // k-group / C row-group
    const int r16  = lane & 15;      // batch col
    const int b0   = blockIdx.x * MB;

    for (int i = tid; i < 2 * MB * 36; i += 512){
        (&h0buf[0][0][0])[i] = 0u;
        (&h1buf[0][0][0])[i] = 0u;
    }

    // ---- A-fragments (fp16, pre-scaled by {log2e, log2e, 2log2e}) ----
    const float gsc[3] = { K_LOG2E, K_LOG2E, K_2LOG2E };
    half8 AW[6][2];
    {
        const float* M0 = isL1 ? Wih1 : Whh0;
        #pragma unroll
        for (int m = 0; m < 6; ++m){
            if (m >= 3 && !isL1) continue;
            const float* Wb = (m < 3) ? M0 : Whh1;
            const float s = gsc[m % 3];
            const float* rowp = Wb + (size_t)((m % 3) * 64 + w * 16 + r16) * HH;
            #pragma unroll
            for (int cw = 0; cw < 2; ++cw){
                const float* pp = rowp + cw * 32 + c * 8;
                AW[m][cw] = mkh8(pkh(s*pp[0], s*pp[1]), pkh(s*pp[2], s*pp[3]),
                                 pkh(s*pp[4], s*pp[5]), pkh(s*pp[6], s*pp[7]));
            }
        }
    }
    half8 Ax[3];
    #pragma unroll
    for (int g = 0; g < 3; ++g){
        if (c == 0 && !isL1){
            const float s = gsc[g];
            const float* rowp = Wih0 + (size_t)(g * 64 + w * 16 + r16) * II;
            Ax[g] = mkh8(pkh(s*rowp[0], s*rowp[1]), pkh(s*rowp[2], s*rowp[3]),
                         pkh(s*rowp[4], s*rowp[5]), 0u);
        } else {
            Ax[g] = mkh8(0u, 0u, 0u, 0u);
        }
    }

    // biases (pre-scaled): row = g*64 + w*16 + 4c + q
    const float* bi = isL1 ? bih1 : bih0;
    const float* bh = isL1 ? bhh1 : bhh0;
    const int rq0 = w * 16 + c * 4;
    f32x4 Br, Bz, Bxn, Bhn;
    #pragma unroll
    for (int q = 0; q < 4; ++q){
        Br[q]  = K_LOG2E  * (bi[      rq0 + q] + bh[      rq0 + q]);
        Bz[q]  = K_LOG2E  * (bi[ 64 + rq0 + q] + bh[ 64 + rq0 + q]);
        Bxn[q] = K_2LOG2E *  bi[128 + rq0 + q];
        Bhn[q] = K_2LOG2E *  bh[128 + rq0 + q];
    }

    f32x4 hp = {0.f, 0.f, 0.f, 0.f};   // fp32 carry of own h slice

    // hoisted per-parity LDS pointers
    const uint32_t* rd0[2] = { &h0buf[0][r16][4*c], &h0buf[1][r16][4*c] };
    const uint32_t* rd1[2] = { &h1buf[0][r16][4*c], &h1buf[1][r16][4*c] };
    uint2* wr0[2] = { (uint2*)&h0buf[0][r16][8*w + 2*c], (uint2*)&h0buf[1][r16][8*w + 2*c] };
    uint2* wr1[2] = { (uint2*)&h1buf[0][r16][8*w + 2*c], (uint2*)&h1buf[1][r16][8*w + 2*c] };

    // double C-set rotation (all indices compile-time via macros)
    f32x4 CrS[2], CzS[2], CxnS[2], ChnS[2];

    // L0: x register stream; prologue preps set[0] (tick 0) incl. x-MFMAs.
    const float* xq = nullptr;
    float2 x0v, x1v, x2v;
    if (!isL1){
        xq = x + (size_t)(b0 + r16) * (TT * II);
        float2 a  = *(const float2*)(xq + 0);
        float2 bb = *(const float2*)(xq + 2);
        float2 cc = *(const float2*)(xq + 4);
        half8 XB = mkh8(pkrtz(a.x, a.y), pkrtz(bb.x, bb.y), pkrtz(cc.x, cc.y), 0u);
        CrS[0]=Br; CzS[0]=Bz; CxnS[0]=Bxn; ChnS[0]=Bhn;
        MF(CrS[0], Ax[0], XB); MF(CzS[0], Ax[1], XB); MF(CxnS[0], Ax[2], XB);
        xq += II;                              // prefetch x(1)
        x0v = *(const float2*)(xq + 0);
        x1v = *(const float2*)(xq + 2);
        x2v = *(const float2*)(xq + 4);
    } else {
        CrS[1]=Br; CzS[1]=Bz; CxnS[1]=Bxn; ChnS[1]=Bhn;   // L1 first tick is parity 1
    }
    __syncthreads();

#define L0TICK(P, TK) do {                                                          \
    half8 H0 = ldq(rd0[P]);                                                         \
    half8 H1 = ldq(rd0[P] + 16);                                                    \
    __builtin_amdgcn_s_setprio(1);                                                  \
    MF(CrS[P],  AW[0][0], H0); MF(CzS[P],  AW[1][0], H0); MF(ChnS[P], AW[2][0], H0);\
    MF(CrS[P],  AW[0][1], H1); MF(CzS[P],  AW[1][1], H1); MF(ChnS[P], AW[2][1], H1);\
    __builtin_amdgcn_s_setprio(0);                                                  \
    uint2 d = gates(CrS[P], CzS[P], CxnS[P], ChnS[P], hp);                          \
    *wr0[(P) ^ 1] = d;                                                              \
    if ((TK) + 1 < TT){   /* pre-barrier prep of next tick (x needs no h) */        \
        half8 XB = mkh8(pkrtz(x0v.x, x0v.y), pkrtz(x1v.x, x1v.y),                   \
                        pkrtz(x2v.x, x2v.y), 0u);                                   \
        CrS[(P)^1]=Br; CzS[(P)^1]=Bz; CxnS[(P)^1]=Bxn; ChnS[(P)^1]=Bhn;             \
        MF(CrS[(P)^1], Ax[0], XB); MF(CzS[(P)^1], Ax[1], XB); MF(CxnS[(P)^1], Ax[2], XB); \
        if ((TK) + 2 < TT){                                                         \
            xq += II;                                                               \
            x0v = *(const float2*)(xq + 0);                                         \
            x1v = *(const float2*)(xq + 2);                                         \
            x2v = *(const float2*)(xq + 4);                                         \
        }                                                                           \
    }                                                                               \
} while(0)

#define L1TICK(P) do {                                                              \
    half8 G0 = ldq(rd0[P]);                                                         \
    half8 G1 = ldq(rd0[P] + 16);                                                    \
    half8 H0 = ldq(rd1[P]);                                                         \
    half8 H1 = ldq(rd1[P] + 16);                                                    \
    __builtin_amdgcn_s_setprio(1);                                                  \
    MF(CrS[P], AW[0][0], G0); MF(CzS[P], AW[1][0], G0); MF(CxnS[P], AW[2][0], G0);  \
    MF(CrS[P], AW[0][1], G1); MF(CzS[P], AW[1][1], G1); MF(CxnS[P], AW[2][1], G1);  \
    MF(CrS[P], AW[3][0], H0); MF(CzS[P], AW[4][0], H0); MF(ChnS[P], AW[5][0], H0);  \
    MF(CrS[P], AW[3][1], H1); MF(CzS[P], AW[4][1], H1); MF(ChnS[P], AW[5][1], H1);  \
    __builtin_amdgcn_s_setprio(0);                                                  \
    uint2 d = gates(CrS[P], CzS[P], CxnS[P], ChnS[P], hp);                          \
    *wr1[(P) ^ 1] = d;                                                              \
    CrS[(P)^1]=Br; CzS[(P)^1]=Bz; CxnS[(P)^1]=Bxn; ChnS[(P)^1]=Bhn;                 \
} while(0)

    // tick 0: L0 only
    if (!isL1) L0TICK(0, 0);
    __syncthreads();
    #pragma unroll 1
    for (int tk = 1; tk < 255; tk += 2){
        if (!isL1) L0TICK(1, tk); else L1TICK(1);
        __syncthreads();
        if (!isL1) L0TICK(0, tk + 1); else L1TICK(0);
        __syncthreads();
    }
    if (!isL1) L0TICK(1, 255); else L1TICK(1);
    __syncthreads();
    if (isL1) L1TICK(0);        // tick 256: L1 finishes h1(255)

#undef L0TICK
#undef L1TICK

    // ---- final FC: out[b] = dot(h1_final[b], Wfc) + bfc ----
    if (isL1){
        float4 wf = *(const float4*)(Wfc + w * 16 + c * 4);
        fcpart[w * 4 + c][r16] =
            hp[0] * wf.x + hp[1] * wf.y + hp[2] * wf.z + hp[3] * wf.w;
    }
    __syncthreads();
    if (tid < MB){
        float s = bfc[0];
        #pragma unroll
        for (int k = 0; k < 16; ++k) s += fcpart[k][tid];
        out[b0 + tid] = s;
    }
}

extern "C" void kernel_launch(void* const* d_in, const int* in_sizes, int n_in,
                              void* d_out, int out_size, void* d_ws, size_t ws_size,
                              hipStream_t stream)
{
    const float* x    = (const float*)d_in[0];
    const float* Wih0 = (const float*)d_in[1];
    const float* Whh0 = (const float*)d_in[2];
    const float* bih0 = (const float*)d_in[3];
    const float* bhh0 = (const float*)d_in[4];
    const float* Wih1 = (const float*)d_in[5];
    const float* Whh1 = (const float*)d_in[6];
    const float* bih1 = (const float*)d_in[7];
    const float* bhh1 = (const float*)d_in[8];
    const float* Wfc  = (const float*)d_in[9];
    const float* bfc  = (const float*)d_in[10];
    float* out = (float*)d_out;

    dim3 grid(4096 / MB), block(512);
    gru2_v7<<<grid, block, 0, stream>>>(x, Wih0, Whh0, bih0, bhh0,
                                        Wih1, Whh1, bih1, bhh1,
                                        Wfc, bfc, out);
}